// Round 1
// baseline (677.026 us; speedup 1.0000x reference)
//
#include <hip/hip_runtime.h>

// DomainAwareStructuralPrior: masks (128,1024,1024) f32 logits -> (128,) f32.
// Pass 1: each WAVE sweeps 32 full-width rows (4 float4 segments/lane/row),
//         binaries packed as bytes-in-u32, horizontal sums via v_sad_u8.
//         All sums are exact integers -> bit-exact vs the fp32 reference.
//         v2: 2-buffer ping-pong prefetch (depth 2, 32 raw VGPRs instead of
//         48), edge bytes packed so cross-lane traffic is 4 shuffles/row
//         instead of 16. Goal: eliminate spill/serialization pathology that
//         held v1 at 0.79 TB/s (12.5% of HBM ceiling).
// Pass 2: 128-thread scoring kernel.

#define N_IMG 128
#define H 1024
#define W 1024
#define WROWS 32                         // rows per wave
#define WAVES_PER_BLOCK 4
#define BROWS (WROWS * WAVES_PER_BLOCK)  // 128 rows per block
#define BLOCKS_PER_IMG (H / BROWS)       // 8
#define NPART (N_IMG * BLOCKS_PER_IMG)   // 1024

static __device__ __forceinline__ unsigned sad8(unsigned a, unsigned b,
                                                unsigned c) {
#if __has_builtin(__builtin_amdgcn_sad_u8)
    return __builtin_amdgcn_sad_u8(a, b, c);
#else
    unsigned s = c;
#pragma unroll
    for (int k = 0; k < 4; ++k) {
        unsigned x = (a >> (8 * k)) & 0xFFu, y = (b >> (8 * k)) & 0xFFu;
        s += (x > y) ? (x - y) : (y - x);
    }
    return s;
#endif
}

__global__ __launch_bounds__(256, 4) void dasp_sums_kernel(
    const float* __restrict__ masks, unsigned* __restrict__ partials) {
    const int blk = blockIdx.x;
    const int img = blk / BLOCKS_PER_IMG;
    const int chunk = blk - img * BLOCKS_PER_IMG;
    const int wave = threadIdx.x >> 6;
    const int lane = threadIdx.x & 63;

    const int y0 = chunk * BROWS + wave * WROWS;  // first compute row
    const int yEnd = y0 + WROWS;                  // bottom halo row index

    const float* __restrict__ base = masks + (size_t)img * (H * W);

    // Fetch one full row: 4 segments, seg s covers cols [s*256, s*256+256),
    // this lane holds cols s*256 + lane*4 .. +3. Rows outside [0,H) -> 0.
    auto fetchRow = [&](int y, float4* f) {
        if (y >= 0 && y < H) {
            const float* row = base + (size_t)y * W + lane * 4;
            f[0] = *reinterpret_cast<const float4*>(row);
            f[1] = *reinterpret_cast<const float4*>(row + 256);
            f[2] = *reinterpret_cast<const float4*>(row + 512);
            f[3] = *reinterpret_cast<const float4*>(row + 768);
        } else {
            f[0] = f[1] = f[2] = f[3] = make_float4(0.f, 0.f, 0.f, 0.f);
        }
    };

    // binary(x) = (x > 0), packed one byte per column: byte j = col j of the
    // lane's 4-col group.
    auto packRow = [&](const float4* f, unsigned* b) {
#pragma unroll
        for (int s = 0; s < 4; ++s) {
            unsigned v = (f[s].x > 0.f) ? 0x00000001u : 0u;
            v |= (f[s].y > 0.f) ? 0x00000100u : 0u;
            v |= (f[s].z > 0.f) ? 0x00010000u : 0u;
            v |= (f[s].w > 0.f) ? 0x01000000u : 0u;
            b[s] = v;
        }
    };

    const bool isL0 = (lane == 0);
    const bool isL63 = (lane == 63);

    unsigned bp[4], bc[4];   // packed binary rows y-1, y
    float4 bufA[4], bufB[4]; // ping-pong raw-row buffers (depth-2 prefetch)

    // Prologue: overlap the two halo-row fetch latencies, then fill the
    // pipeline. bufA holds rows == y0+1 (mod 2), bufB rows == y0 (mod 2).
    fetchRow(y0 - 1, bufA);
    fetchRow(y0, bufB);
    packRow(bufA, bp);
    fetchRow(y0 + 1, bufA);
    packRow(bufB, bc);
    fetchRow(y0 + 2, bufB);

    unsigned area = 0, conn = 0, A1 = 0, A2 = 0;

    // One pipeline step: buf holds raw row y+1 (loads in flight). Pack it,
    // immediately reissue the same buffer for row y+3 (same parity), then
    // do the SWAR neighbor math for compute row y.
    auto step = [&](float4(&buf)[4], int y) {
        unsigned bn[4];
        packRow(buf, bn);  // row y+1 (compiler inserts the vmcnt wait here)
        if (y + 3 <= yEnd) fetchRow(y + 3, buf);  // refill; depth-2 prefetch

        // vertical 3-row column sums, one byte per column (max 3, no carry)
        unsigned c[4];
#pragma unroll
        for (int s = 0; s < 4; ++s) c[s] = bp[s] + bc[s] + bn[s];

        // Pack the 4 segment-edge bytes into one word each, so the whole
        // row's cross-lane traffic is 2 shuffles + 2 broadcasts (was 16).
        // eH byte s = top byte of c[s]  (column s*256 + lane*4 + 3)
        // eL byte s = low byte of c[s]  (column s*256 + lane*4)
        const unsigned eH = (c[0] >> 24) | ((c[1] >> 16) & 0xFF00u) |
                            ((c[2] >> 8) & 0xFF0000u) | (c[3] & 0xFF000000u);
        const unsigned eL = (c[0] & 0xFFu) | ((c[1] & 0xFFu) << 8) |
                            ((c[2] & 0xFFu) << 16) | (c[3] << 24);
        unsigned eN = __shfl_up(eH, 1);    // left-neighbor columns
        const unsigned hi63 = __shfl(eH, 63);
        unsigned eM = __shfl_down(eL, 1);  // right-neighbor columns
        const unsigned lo0 = __shfl(eL, 0);
        // lane 0: left neighbor of segment s is segment s-1's lane-63 top
        // byte (0 for s=0); lane 63: right neighbor of segment s is segment
        // s+1's lane-0 low byte (0 for s=3).
        eN = isL0 ? (hi63 << 8) : eN;
        eM = isL63 ? (lo0 >> 8) : eM;

#pragma unroll
        for (int s = 0; s < 4; ++s) {
            const unsigned left = (c[s] << 8) | ((eN >> (8 * s)) & 0xFFu);
            const unsigned right =
                (c[s] >> 8) | (((eM >> (8 * s)) & 0xFFu) << 24);
            // 8-neighbor count per column byte: box sum minus center
            // (max 9 per byte -> no carries; n >= b so sub has no borrows)
            const unsigned n = c[s] + left + right - bc[s];

            const unsigned bmask = (bc[s] << 8) - bc[s];  // b ? 0xFF : 0x00
            area = sad8(bc[s], 0u, area);                 // sum b
            A2 = sad8(n, 0u, A2);                         // sum n
            A1 = sad8(n, bc[s] << 2, A1);                 // sum |n - 4b|
            conn = sad8(n & bmask, 0u, conn);             // sum n*b
        }

#pragma unroll
        for (int s = 0; s < 4; ++s) {
            bp[s] = bc[s];
            bc[s] = bn[s];
        }
    };

    // WROWS is even: manual 2-step unroll keeps the buffer choice a
    // compile-time constant (runtime-indexed arrays would go to scratch).
    for (int y = y0; y < yEnd; y += 2) {
        step(bufA, y);
        step(bufB, y + 1);
    }

    // per-pixel: max(n-4b,0) = (|n-4b| + n - 4b)/2 ; summed per lane (even)
    int a = (int)area;
    int cn = (int)conn;
    int p = (int)((A1 + A2 - 4u * area) >> 1);

#pragma unroll
    for (int m = 32; m >= 1; m >>= 1) {
        a += __shfl_xor(a, m);
        cn += __shfl_xor(cn, m);
        p += __shfl_xor(p, m);
    }

    __shared__ int sA[WAVES_PER_BLOCK], sC[WAVES_PER_BLOCK],
        sP[WAVES_PER_BLOCK];
    if (lane == 0) {
        sA[wave] = a;
        sC[wave] = cn;
        sP[wave] = p;
    }
    __syncthreads();
    if (threadIdx.x == 0) {
        int ta = 0, tc = 0, tp = 0;
#pragma unroll
        for (int wv = 0; wv < WAVES_PER_BLOCK; ++wv) {
            ta += sA[wv];
            tc += sC[wv];
            tp += sP[wv];
        }
        partials[blk] = (unsigned)ta;
        partials[NPART + blk] = (unsigned)tc;
        partials[2 * NPART + blk] = (unsigned)tp;
    }
}

__global__ void dasp_score_kernel(const unsigned* __restrict__ partials,
                                  float* __restrict__ out) {
    const int n = threadIdx.x;
    if (n >= N_IMG) return;
    unsigned a = 0, c = 0, p = 0;
#pragma unroll
    for (int k = 0; k < BLOCKS_PER_IMG; ++k) {
        a += partials[n * BLOCKS_PER_IMG + k];
        c += partials[NPART + n * BLOCKS_PER_IMG + k];
        p += partials[2 * NPART + n * BLOCKS_PER_IMG + k];
    }
    const float areaf = (float)a;
    const float ratio = areaf / (float)(H * W);
    const float area_score = (ratio >= 0.001f && ratio <= 0.5f) ? 1.0f : 0.1f;
    const float safe = (a > 0) ? areaf : 1.0f;
    const float connf = (float)c;
    const float comp =
        (c > 0) ? fminf(1.0f, 10.0f / (connf / safe + 1e-6f)) : 0.1f;
    const float perf = (float)p;
    const float par = perf / safe;
    const float shape =
        (a > 0)
            ? ((par <= 100.0f) ? 1.0f : fmaxf(0.1f, 100.0f / (par + 1e-6f)))
            : 0.1f;
    const float v = 0.4f * area_score + 0.3f * comp + 0.3f * shape;
    out[n] = fmaxf(0.05f, v);
}

extern "C" void kernel_launch(void* const* d_in, const int* in_sizes, int n_in,
                              void* d_out, int out_size, void* d_ws,
                              size_t ws_size, hipStream_t stream) {
    const float* masks = (const float*)d_in[0];
    float* out = (float*)d_out;
    unsigned* partials = (unsigned*)d_ws;  // 3 * 1024 * 4 B = 12 KB

    dasp_sums_kernel<<<dim3(N_IMG * BLOCKS_PER_IMG), dim3(256), 0, stream>>>(
        masks, partials);
    dasp_score_kernel<<<dim3(1), dim3(128), 0, stream>>>(partials, out);
}

// Round 4
// 651.342 us; speedup vs baseline: 1.0394x; 1.0394x over previous
//
#include <hip/hip_runtime.h>

// DomainAwareStructuralPrior: masks (128,1024,1024) f32 logits -> (128,) f32.
// Pass 1: each WAVE sweeps 16 full-width rows (4 float4 segments/lane/row),
//         binaries packed as bytes-in-u32, horizontal sums via v_sad_u8.
//         All sums are exact integers -> bit-exact vs the fp32 reference.
//         v3 (diagnostic): 16 rows/wave + 2048 blocks (halved serial chain,
//         doubled block parallelism) + nontemporal row loads (read-once
//         stream, don't thrash L2). If this doesn't move dur_us, the bench
//         is bound by the harness's 2x2GiB poison fills (2x337us = 674us),
//         not by this kernel.
//         v3b: use clang ext_vector f32x4 (HIP float4 is a class type ->
//         __builtin_nontemporal_load rejects it).
// Pass 2: 128-thread scoring kernel.

#define N_IMG 128
#define H 1024
#define W 1024
#define WROWS 16                         // rows per wave
#define WAVES_PER_BLOCK 4
#define BROWS (WROWS * WAVES_PER_BLOCK)  // 64 rows per block
#define BLOCKS_PER_IMG (H / BROWS)       // 16
#define NPART (N_IMG * BLOCKS_PER_IMG)   // 2048

typedef float f32x4 __attribute__((ext_vector_type(4)));

static __device__ __forceinline__ unsigned sad8(unsigned a, unsigned b,
                                                unsigned c) {
#if __has_builtin(__builtin_amdgcn_sad_u8)
    return __builtin_amdgcn_sad_u8(a, b, c);
#else
    unsigned s = c;
#pragma unroll
    for (int k = 0; k < 4; ++k) {
        unsigned x = (a >> (8 * k)) & 0xFFu, y = (b >> (8 * k)) & 0xFFu;
        s += (x > y) ? (x - y) : (y - x);
    }
    return s;
#endif
}

__global__ __launch_bounds__(256, 4) void dasp_sums_kernel(
    const float* __restrict__ masks, unsigned* __restrict__ partials) {
    const int blk = blockIdx.x;
    const int img = blk / BLOCKS_PER_IMG;
    const int chunk = blk - img * BLOCKS_PER_IMG;
    const int wave = threadIdx.x >> 6;
    const int lane = threadIdx.x & 63;

    const int y0 = chunk * BROWS + wave * WROWS;  // first compute row
    const int yEnd = y0 + WROWS;                  // bottom halo row index

    const float* __restrict__ base = masks + (size_t)img * (H * W);

    // Fetch one full row: 4 segments, seg s covers cols [s*256, s*256+256),
    // this lane holds cols s*256 + lane*4 .. +3. Rows outside [0,H) -> 0.
    // Nontemporal: each row is consumed once (halo reuse is negligible and
    // crosses blocks/XCDs) -- keep the stream out of L2's way.
    auto fetchRow = [&](int y, f32x4* f) {
        if (y >= 0 && y < H) {
            const f32x4* row =
                reinterpret_cast<const f32x4*>(base + (size_t)y * W) + lane;
            f[0] = __builtin_nontemporal_load(row);
            f[1] = __builtin_nontemporal_load(row + 64);
            f[2] = __builtin_nontemporal_load(row + 128);
            f[3] = __builtin_nontemporal_load(row + 192);
        } else {
            f[0] = f[1] = f[2] = f[3] = (f32x4)(0.f);
        }
    };

    // binary(x) = (x > 0), packed one byte per column: byte j = col j of the
    // lane's 4-col group.
    auto packRow = [&](const f32x4* f, unsigned* b) {
#pragma unroll
        for (int s = 0; s < 4; ++s) {
            unsigned v = (f[s][0] > 0.f) ? 0x00000001u : 0u;
            v |= (f[s][1] > 0.f) ? 0x00000100u : 0u;
            v |= (f[s][2] > 0.f) ? 0x00010000u : 0u;
            v |= (f[s][3] > 0.f) ? 0x01000000u : 0u;
            b[s] = v;
        }
    };

    const bool isL0 = (lane == 0);
    const bool isL63 = (lane == 63);

    unsigned bp[4], bc[4];    // packed binary rows y-1, y
    f32x4 bufA[4], bufB[4];   // ping-pong raw-row buffers (depth-2 prefetch)

    // Prologue: overlap the two halo-row fetch latencies, then fill the
    // pipeline. bufA holds rows == y0+1 (mod 2), bufB rows == y0 (mod 2).
    fetchRow(y0 - 1, bufA);
    fetchRow(y0, bufB);
    packRow(bufA, bp);
    fetchRow(y0 + 1, bufA);
    packRow(bufB, bc);
    fetchRow(y0 + 2, bufB);

    unsigned area = 0, conn = 0, A1 = 0, A2 = 0;

    // One pipeline step: buf holds raw row y+1 (loads in flight). Pack it,
    // immediately reissue the same buffer for row y+3 (same parity), then
    // do the SWAR neighbor math for compute row y.
    auto step = [&](f32x4(&buf)[4], int y) {
        unsigned bn[4];
        packRow(buf, bn);  // row y+1 (compiler inserts the vmcnt wait here)
        if (y + 3 <= yEnd) fetchRow(y + 3, buf);  // refill; depth-2 prefetch

        // vertical 3-row column sums, one byte per column (max 3, no carry)
        unsigned c[4];
#pragma unroll
        for (int s = 0; s < 4; ++s) c[s] = bp[s] + bc[s] + bn[s];

        // Pack the 4 segment-edge bytes into one word each, so the whole
        // row's cross-lane traffic is 2 shuffles + 2 broadcasts (was 16).
        // eH byte s = top byte of c[s]  (column s*256 + lane*4 + 3)
        // eL byte s = low byte of c[s]  (column s*256 + lane*4)
        const unsigned eH = (c[0] >> 24) | ((c[1] >> 16) & 0xFF00u) |
                            ((c[2] >> 8) & 0xFF0000u) | (c[3] & 0xFF000000u);
        const unsigned eL = (c[0] & 0xFFu) | ((c[1] & 0xFFu) << 8) |
                            ((c[2] & 0xFFu) << 16) | (c[3] << 24);
        unsigned eN = __shfl_up(eH, 1);  // left-neighbor columns
        const unsigned hi63 = __shfl(eH, 63);
        unsigned eM = __shfl_down(eL, 1);  // right-neighbor columns
        const unsigned lo0 = __shfl(eL, 0);
        // lane 0: left neighbor of segment s is segment s-1's lane-63 top
        // byte (0 for s=0); lane 63: right neighbor of segment s is segment
        // s+1's lane-0 low byte (0 for s=3).
        eN = isL0 ? (hi63 << 8) : eN;
        eM = isL63 ? (lo0 >> 8) : eM;

#pragma unroll
        for (int s = 0; s < 4; ++s) {
            const unsigned left = (c[s] << 8) | ((eN >> (8 * s)) & 0xFFu);
            const unsigned right =
                (c[s] >> 8) | (((eM >> (8 * s)) & 0xFFu) << 24);
            // 8-neighbor count per column byte: box sum minus center
            // (max 9 per byte -> no carries; n >= b so sub has no borrows)
            const unsigned n = c[s] + left + right - bc[s];

            const unsigned bmask = (bc[s] << 8) - bc[s];  // b ? 0xFF : 0x00
            area = sad8(bc[s], 0u, area);                 // sum b
            A2 = sad8(n, 0u, A2);                         // sum n
            A1 = sad8(n, bc[s] << 2, A1);                 // sum |n - 4b|
            conn = sad8(n & bmask, 0u, conn);             // sum n*b
        }

#pragma unroll
        for (int s = 0; s < 4; ++s) {
            bp[s] = bc[s];
            bc[s] = bn[s];
        }
    };

    // WROWS is even: manual 2-step unroll keeps the buffer choice a
    // compile-time constant (runtime-indexed arrays would go to scratch).
    for (int y = y0; y < yEnd; y += 2) {
        step(bufA, y);
        step(bufB, y + 1);
    }

    // per-pixel: max(n-4b,0) = (|n-4b| + n - 4b)/2 ; summed per lane (even)
    int a = (int)area;
    int cn = (int)conn;
    int p = (int)((A1 + A2 - 4u * area) >> 1);

#pragma unroll
    for (int m = 32; m >= 1; m >>= 1) {
        a += __shfl_xor(a, m);
        cn += __shfl_xor(cn, m);
        p += __shfl_xor(p, m);
    }

    __shared__ int sA[WAVES_PER_BLOCK], sC[WAVES_PER_BLOCK],
        sP[WAVES_PER_BLOCK];
    if (lane == 0) {
        sA[wave] = a;
        sC[wave] = cn;
        sP[wave] = p;
    }
    __syncthreads();
    if (threadIdx.x == 0) {
        int ta = 0, tc = 0, tp = 0;
#pragma unroll
        for (int wv = 0; wv < WAVES_PER_BLOCK; ++wv) {
            ta += sA[wv];
            tc += sC[wv];
            tp += sP[wv];
        }
        partials[blk] = (unsigned)ta;
        partials[NPART + blk] = (unsigned)tc;
        partials[2 * NPART + blk] = (unsigned)tp;
    }
}

__global__ void dasp_score_kernel(const unsigned* __restrict__ partials,
                                  float* __restrict__ out) {
    const int n = threadIdx.x;
    if (n >= N_IMG) return;
    unsigned a = 0, c = 0, p = 0;
#pragma unroll
    for (int k = 0; k < BLOCKS_PER_IMG; ++k) {
        a += partials[n * BLOCKS_PER_IMG + k];
        c += partials[NPART + n * BLOCKS_PER_IMG + k];
        p += partials[2 * NPART + n * BLOCKS_PER_IMG + k];
    }
    const float areaf = (float)a;
    const float ratio = areaf / (float)(H * W);
    const float area_score = (ratio >= 0.001f && ratio <= 0.5f) ? 1.0f : 0.1f;
    const float safe = (a > 0) ? areaf : 1.0f;
    const float connf = (float)c;
    const float comp =
        (c > 0) ? fminf(1.0f, 10.0f / (connf / safe + 1e-6f)) : 0.1f;
    const float perf = (float)p;
    const float par = perf / safe;
    const float shape =
        (a > 0)
            ? ((par <= 100.0f) ? 1.0f : fmaxf(0.1f, 100.0f / (par + 1e-6f)))
            : 0.1f;
    const float v = 0.4f * area_score + 0.3f * comp + 0.3f * shape;
    out[n] = fmaxf(0.05f, v);
}

extern "C" void kernel_launch(void* const* d_in, const int* in_sizes, int n_in,
                              void* d_out, int out_size, void* d_ws,
                              size_t ws_size, hipStream_t stream) {
    const float* masks = (const float*)d_in[0];
    float* out = (float*)d_out;
    unsigned* partials = (unsigned*)d_ws;  // 3 * 2048 * 4 B = 24 KB

    dasp_sums_kernel<<<dim3(N_IMG * BLOCKS_PER_IMG), dim3(256), 0, stream>>>(
        masks, partials);
    dasp_score_kernel<<<dim3(1), dim3(128), 0, stream>>>(partials, out);
}